// Round 13
// baseline (376.012 us; speedup 1.0000x reference)
//
#include <hip/hip_runtime.h>
#include <hip/hip_bf16.h>

typedef __hip_bfloat16 bf16;
typedef __attribute__((ext_vector_type(8))) short short8;
typedef __attribute__((ext_vector_type(4))) float f32x4;

#define NROI 200
#define EPB 6400    // edges per count block (== SPB; 256 blocks -> all CUs)
#define SPB 6400    // edges per scatter block

__device__ __forceinline__ float u2f(unsigned short u) {
  return __uint_as_float(((unsigned)u) << 16);
}
__device__ __forceinline__ float lo16(unsigned u) { return __uint_as_float(u << 16); }
__device__ __forceinline__ float hi16(unsigned u) { return __uint_as_float(u & 0xffff0000u); }
__device__ __forceinline__ float b2f(bf16 v) { return __bfloat162float(v); }
__device__ __forceinline__ unsigned short f2us(float f) {
  union { bf16 b; unsigned short u; } c;
  c.b = __float2bfloat16(f);
  return c.u;
}

__device__ __forceinline__ float mishf(float x) {
  float sp = (x > 20.0f) ? x : log1pf(expf(x));
  return x * tanhf(sp);
}

// ---------------- dtype detection ----------------
__global__ __launch_bounds__(256) void detect_kernel(const unsigned short* xu,
                                                     const unsigned* eiw,
                                                     int* flags) {
  int tid = threadIdx.x;
  int sane = 0, zodd = 0;
  for (int i = tid; i < 4096; i += 256) {
    unsigned short u = xu[2 * i];
    unsigned e = (u >> 7) & 0xFF;
    if (u == 0 || (e >= 100 && e <= 134)) sane++;
  }
  for (int i = tid; i < 4096; i += 256) {
    if (eiw[2 * i + 1] == 0) zodd++;
  }
  __shared__ int s1[256], s2[256];
  s1[tid] = sane; s2[tid] = zodd;
  __syncthreads();
  for (int off = 128; off > 0; off >>= 1) {
    if (tid < off) { s1[tid] += s1[tid + off]; s2[tid] += s2[tid + off]; }
    __syncthreads();
  }
  if (tid == 0) {
    flags[0] = (s1[0] < 2048) ? 1 : 0;
    flags[1] = (s2[0] > 2048) ? 1 : 0;
  }
}

// ---------------- weight canonicalization + swizzles (merged) ----------------
struct WArgs {
  const void* src[16];
  int n[16];
  int off[16];
};

// y = 0..15: convert tensor -> bf16 at cw+off.
// y = 16: swizzle W1 (200x128, KC=7, NT=8) from source; y = 17: W2 (128x64, KC=4, NT=4).
__global__ __launch_bounds__(256) void convert_weights(WArgs a, bf16* base,
                                                       unsigned short* __restrict__ w1swz,
                                                       unsigned short* __restrict__ w2swz,
                                                       const int* flags) {
  int t = blockIdx.y;
  int i = blockIdx.x * 256 + threadIdx.x;
  int isf32 = flags[0];
  if (t < 16) {
    if (i >= a.n[t]) return;
    bf16* dst = base + a.off[t];
    if (isf32) dst[i] = __float2bfloat16(((const float*)a.src[t])[i]);
    else ((unsigned short*)dst)[i] = ((const unsigned short*)a.src[t])[i];
    return;
  }
  int w1 = (t == 16);
  int K  = w1 ? 200 : 128;
  int NT = w1 ? 8 : 4;
  int KC = w1 ? 7 : 4;
  int total = KC * NT * 512;
  if (i >= total) return;
  int e = i & 7;
  int l = (i >> 3) & 63;
  int tt = (i >> 9) % NT;
  int kc = i / (NT * 512);
  int k = kc * 32 + (l >> 4) * 8 + e;
  int c = tt * 16 + (l & 15);
  unsigned short v = 0;
  if (k < K) {
    const void* src = w1 ? a.src[0] : a.src[2];
    if (isf32) v = f2us(((const float*)src)[k * (NT * 16) + c]);
    else v = ((const unsigned short*)src)[k * (NT * 16) + c];
  }
  (w1 ? w1swz : w2swz)[i] = v;
}

// ---------------- LDS-histogram CSR build ----------------

__global__ __launch_bounds__(1024, 1) void count_lds(const int* __restrict__ ei,
                                                     const void* __restrict__ ea,
                                                     const int* __restrict__ flags,
                                                     unsigned* __restrict__ cnt8g,
                                                     unsigned* __restrict__ ws16g,
                                                     unsigned char* __restrict__ rank8,
                                                     int NU, int NW, int E) {
  extern __shared__ unsigned smem[];
  unsigned* s_cnt = smem;        // NU u32
  unsigned* s_ws  = smem + NU;   // NW u32
  int tid = threadIdx.x;
  int blk = blockIdx.x;
  for (int i = tid; i < NU + NW; i += 1024) smem[i] = 0;
  __syncthreads();
  int is64 = flags[1], isf32 = flags[0];
  long long base = (long long)blk * EPB;
  for (int k = 0; k < EPB; k += 1024) {
    int ko = k + tid;
    long long e = base + ko;
    if (ko < EPB && e < E) {
      int c = is64 ? __builtin_nontemporal_load(&ei[2 * ((long long)E + e)])
                   : __builtin_nontemporal_load(&ei[(long long)E + e]);
      float w = isf32 ? __builtin_nontemporal_load(&((const float*)ea)[e])
                      : u2f(__builtin_nontemporal_load(&((const unsigned short*)ea)[e]));
      w = fminf(fmaxf(w, 0.0f), 15.0f);
      unsigned sh = (unsigned)(c & 3) * 8;
      unsigned old = atomicAdd(&s_cnt[c >> 2], 1u << sh);
      rank8[e] = (unsigned char)((old >> sh) & 0xFF);
      unsigned wi = __float2uint_rn(w * 4096.0f);
      atomicAdd(&s_ws[c >> 1], (c & 1) ? (wi << 16) : wi);
    }
  }
  __syncthreads();
  for (int i = tid; i < NU; i += 1024)
    __builtin_nontemporal_store(s_cnt[i], &cnt8g[(size_t)blk * NU + i]);
  for (int i = tid; i < NW; i += 1024)
    __builtin_nontemporal_store(s_ws[i], &ws16g[(size_t)blk * NW + i]);
}

__global__ __launch_bounds__(256) void reduce_r1(unsigned* __restrict__ cnt8g,
                                                 const unsigned* __restrict__ ws16g,
                                                 unsigned* __restrict__ cntpart,
                                                 unsigned* __restrict__ wspart,
                                                 int NU, int NW, int nblk, int bpg) {
  int col = blockIdx.x * 256 + threadIdx.x;
  int gy = blockIdx.y;
  if (col >= NU) return;
  unsigned run = 0;
  unsigned r0 = 0, r1 = 0, r2 = 0, r3 = 0;
  int b0 = gy * bpg;
  int be = b0 + bpg; if (be > nblk) be = nblk;
  for (int b = b0; b < be; ++b) {
    unsigned v = cnt8g[(size_t)b * NU + col];
    cnt8g[(size_t)b * NU + col] = run;
    run += v;                       // SWAR-safe: per-node totals < 256
    unsigned wA = ws16g[(size_t)b * NW + 2 * col];
    unsigned wB = ws16g[(size_t)b * NW + 2 * col + 1];
    r0 += wA & 0xFFFF; r1 += wA >> 16;
    r2 += wB & 0xFFFF; r3 += wB >> 16;
  }
  cntpart[(size_t)gy * NU + col] = run;
  unsigned* wp = &wspart[((size_t)gy * NU + col) * 4];
  wp[0] = r0; wp[1] = r1; wp[2] = r2; wp[3] = r3;
}

// 4-group prefix -> gybase; totals -> cnt[n]; dis; + per-1024-node block sums
__global__ __launch_bounds__(256) void combine_k(const unsigned* __restrict__ cntpart,
                                                 const unsigned* __restrict__ wspart,
                                                 unsigned* __restrict__ gybase,
                                                 int* __restrict__ cnt,
                                                 float* __restrict__ dis,
                                                 int* __restrict__ bsum,
                                                 int NU, int N) {
  __shared__ int ts[256];
  int col = blockIdx.x * 256 + threadIdx.x;
  int mysum = 0;
  if (col < NU) {
    unsigned g = 0;
#pragma unroll
    for (int gy = 0; gy < 4; ++gy) {
      unsigned t = cntpart[(size_t)gy * NU + col];
      gybase[(size_t)gy * NU + col] = g;
      g += t;
    }
    unsigned ws[4] = {0, 0, 0, 0};
#pragma unroll
    for (int gy = 0; gy < 4; ++gy) {
      const unsigned* wp = &wspart[((size_t)gy * NU + col) * 4];
#pragma unroll
      for (int j = 0; j < 4; ++j) ws[j] += wp[j];
    }
#pragma unroll
    for (int j = 0; j < 4; ++j) {
      int n = 4 * col + j;
      if (n < N) {
        int cj = (int)((g >> (8 * j)) & 0xFF);
        cnt[n] = cj;
        mysum += cj;
        dis[n] = rsqrtf(1.0f + (float)ws[j] * 0.000244140625f);
      }
    }
  }
  int tid = threadIdx.x;
  ts[tid] = mysum;
  __syncthreads();
  for (int off = 128; off > 0; off >>= 1) {
    if (tid < off) ts[tid] += ts[tid + off];
    __syncthreads();
  }
  if (tid == 0) bsum[blockIdx.x] = ts[0];
}

// scan over cnt -> ptr; per-block base computed inline from bsum (phase2 folded)
__global__ __launch_bounds__(256) void scan_phase3(const int* __restrict__ cnt,
                                                   const int* __restrict__ bsum,
                                                   int* __restrict__ ptr,
                                                   int nb, int N) {
  __shared__ int ts[256];
  int blk = blockIdx.x;
  int tid = threadIdx.x;
  int bpre = 0;
  for (int i = 0; i < blk; ++i) bpre += bsum[i];
  int base = blk * 1024 + tid * 4;
  int c0 = 0, c1 = 0, c2 = 0, c3 = 0;
  if (base + 0 < N) c0 = cnt[base + 0];
  if (base + 1 < N) c1 = cnt[base + 1];
  if (base + 2 < N) c2 = cnt[base + 2];
  if (base + 3 < N) c3 = cnt[base + 3];
  ts[tid] = c0 + c1 + c2 + c3;
  __syncthreads();
  for (int off = 1; off < 256; off <<= 1) {
    int v = ts[tid];
    if (tid >= off) v += ts[tid - off];
    __syncthreads();
    ts[tid] = v;
    __syncthreads();
  }
  int run = bpre + (tid ? ts[tid - 1] : 0);
  if (base + 0 < N) { ptr[base + 0] = run; run += c0; }
  if (base + 1 < N) { ptr[base + 1] = run; run += c1; }
  if (base + 2 < N) { ptr[base + 2] = run; run += c2; }
  if (base + 3 < N) { ptr[base + 3] = run; run += c3; }
  if (blk == nb - 1 && tid == 255) ptr[N] = bpre + ts[255];
}

__global__ __launch_bounds__(1024, 1) void scatter_lds(const int* __restrict__ ei,
                                                       const void* __restrict__ ea,
                                                       const int* __restrict__ flags,
                                                       const float* __restrict__ dis,
                                                       const int* __restrict__ ptr,
                                                       const unsigned* __restrict__ cnt8g,
                                                       const unsigned* __restrict__ gybase,
                                                       const unsigned char* __restrict__ rank8,
                                                       long long* __restrict__ epair,
                                                       int NU, int bpg, int E) {
  extern __shared__ unsigned smem[];
  unsigned* s_pb = smem;        // per-count-block bases
  unsigned* s_gb = smem + NU;   // group bases
  int tid = threadIdx.x;
  int blk = blockIdx.x;         // == count block (EPB == SPB)
  int gy = blk / bpg;
  for (int i = tid; i < NU; i += 1024) s_pb[i] = cnt8g[(size_t)blk * NU + i];
  for (int i = tid; i < NU; i += 1024) s_gb[i] = gybase[(size_t)gy * NU + i];
  __syncthreads();
  int is64 = flags[1], isf32 = flags[0];
  long long base = (long long)blk * SPB;
  for (int k = 0; k < SPB; k += 1024) {
    int ko = k + tid;
    long long e = base + ko;
    if (ko < SPB && e < E) {
      int r = is64 ? __builtin_nontemporal_load(&ei[2 * e])
                   : __builtin_nontemporal_load(&ei[e]);
      int c = is64 ? __builtin_nontemporal_load(&ei[2 * ((long long)E + e)])
                   : __builtin_nontemporal_load(&ei[(long long)E + e]);
      float w = isf32 ? __builtin_nontemporal_load(&((const float*)ea)[e])
                      : u2f(__builtin_nontemporal_load(&((const unsigned short*)ea)[e]));
      float nrm = dis[r] * w * dis[c];
      unsigned sh = (unsigned)(c & 3) * 8;
      unsigned p1 = (s_pb[c >> 2] >> sh) & 0xFF;
      unsigned p2 = (s_gb[c >> 2] >> sh) & 0xFF;
      int idx = ptr[c] + (int)p1 + (int)p2 + (int)rank8[e];
      long long pr = (long long)((unsigned long long)__float_as_uint(nrm) << 32) |
                     (unsigned)r;
      __builtin_nontemporal_store(pr, &epair[idx]);
    }
  }
}

// ---------------- MFMA GEMM ----------------
// A read directly; dtype from flags[0] if DYN, else bf16. K-chunks fully
// valid or fully zero (Ktrue=200: chunks at k0 in {200,208,216} are zero).
template<int KC, int NT, int DYN>
__global__ __launch_bounds__(256) void gemm_mfma(const void* __restrict__ A,
                                                 int Ktrue,
                                                 const int* __restrict__ flags,
                                                 const unsigned short* __restrict__ Wswz,
                                                 unsigned short* __restrict__ H,
                                                 int M) {
  int wid = threadIdx.x >> 6, lane = threadIdx.x & 63;
  int row0 = (blockIdx.x * 4 + wid) * 16;
  if (row0 >= M) return;
  constexpr int NC = NT * 16;
  int isf32 = DYN ? flags[0] : 0;
  f32x4 acc[NT];
#pragma unroll
  for (int t = 0; t < NT; ++t) acc[t] = {0.f, 0.f, 0.f, 0.f};
  int arow = row0 + (lane & 15);
  int kbase = (lane >> 4) * 8;
  const float* Af = (const float*)A;
  const unsigned short* Au = (const unsigned short*)A;
#pragma unroll
  for (int kc = 0; kc < KC; ++kc) {
    int k0 = kbase + kc * 32;
    short8 a = {0, 0, 0, 0, 0, 0, 0, 0};
    if (k0 + 8 <= Ktrue) {
      size_t off = (size_t)arow * Ktrue + k0;
      if (DYN && isf32) {
        f32x4 f0 = __builtin_nontemporal_load((const f32x4*)&Af[off]);
        f32x4 f1 = __builtin_nontemporal_load((const f32x4*)&Af[off + 4]);
        a[0] = (short)f2us(f0[0]); a[1] = (short)f2us(f0[1]);
        a[2] = (short)f2us(f0[2]); a[3] = (short)f2us(f0[3]);
        a[4] = (short)f2us(f1[0]); a[5] = (short)f2us(f1[1]);
        a[6] = (short)f2us(f1[2]); a[7] = (short)f2us(f1[3]);
      } else {
        a = *(const short8*)&Au[off];
      }
    }
#pragma unroll
    for (int t = 0; t < NT; ++t) {
      short8 b = *(const short8*)&Wswz[((kc * NT + t) * 64 + lane) * 8];
      acc[t] = __builtin_amdgcn_mfma_f32_16x16x32_bf16(a, b, acc[t], 0, 0, 0);
    }
  }
  int orow = row0 + (lane >> 4) * 4;
  int ocol = lane & 15;
#pragma unroll
  for (int t = 0; t < NT; ++t)
#pragma unroll
    for (int r = 0; r < 4; ++r)
      H[(size_t)(orow + r) * NC + t * 16 + ocol] = f2us(acc[t][r]);
}

// ---------------- aggregations ----------------
// conv1: full wave per node; lane owns uint 'lane' (2 of 128 feats).
__global__ __launch_bounds__(256) void agg_mish128(const unsigned* __restrict__ hu,
                                                   const float* __restrict__ dis,
                                                   const int* __restrict__ ptr,
                                                   const long long* __restrict__ ep,
                                                   const bf16* __restrict__ bias,
                                                   unsigned* __restrict__ g, int N) {
  int w = threadIdx.x >> 6, lane = threadIdx.x & 63;
  int n = blockIdx.x * 4 + w;
  float dn = dis[n];
  float self = dn * dn;
  unsigned u = hu[((unsigned)n << 6) + lane];
  float acc0 = lo16(u) * self;
  float acc1 = hi16(u) * self;
  int e0 = ptr[n], e1 = ptr[n + 1];
  for (int base = e0; base < e1; base += 64) {
    long long myp = 0;
    if (base + lane < e1) myp = __builtin_nontemporal_load(&ep[base + lane]);
    int mx = (int)(unsigned)myp;
    int my = (int)(myp >> 32);
    int m = e1 - base; if (m > 64) m = 64;
    int j = 0;
    for (; j + 8 <= m; j += 8) {
      unsigned uu[8]; float ww[8];
#pragma unroll
      for (int q = 0; q < 8; ++q) {
        unsigned rr = (unsigned)__builtin_amdgcn_readlane(mx, j + q);
        uu[q] = hu[(rr << 6) + lane];
        ww[q] = __uint_as_float(__builtin_amdgcn_readlane(my, j + q));
      }
#pragma unroll
      for (int q = 0; q < 8; ++q) {
        acc0 += lo16(uu[q]) * ww[q];
        acc1 += hi16(uu[q]) * ww[q];
      }
    }
    for (; j < m; ++j) {
      unsigned rr = (unsigned)__builtin_amdgcn_readlane(mx, j);
      float ww = __uint_as_float(__builtin_amdgcn_readlane(my, j));
      unsigned uu = hu[(rr << 6) + lane];
      acc0 += lo16(uu) * ww;
      acc1 += hi16(uu) * ww;
    }
  }
  unsigned bb = ((const unsigned*)bias)[lane];
  float m0 = mishf(acc0 + lo16(bb));
  float m1 = mishf(acc1 + hi16(bb));
  __builtin_nontemporal_store(((unsigned)f2us(m1) << 16) | f2us(m0),
                              &g[((unsigned)n << 6) + lane]);
}

// conv2 + readout: full wave per node; lane owns ONE of 64 feats.
__global__ __launch_bounds__(256) void agg_mish64_ro(const unsigned short* __restrict__ hus,
                                                     const float* __restrict__ dis,
                                                     const int* __restrict__ ptr,
                                                     const long long* __restrict__ ep,
                                                     const bf16* __restrict__ bias,
                                                     const bf16* __restrict__ Wro,
                                                     const bf16* __restrict__ bro,
                                                     float* __restrict__ out8, int N) {
  int w = threadIdx.x >> 6, lane = threadIdx.x & 63;
  int n = blockIdx.x * 4 + w;
  float dn = dis[n];
  float self = dn * dn;
  float acc = u2f(hus[((unsigned)n << 6) + lane]) * self;
  int e0 = ptr[n], e1 = ptr[n + 1];
  for (int base = e0; base < e1; base += 64) {
    long long myp = 0;
    if (base + lane < e1) myp = __builtin_nontemporal_load(&ep[base + lane]);
    int mx = (int)(unsigned)myp;
    int my = (int)(myp >> 32);
    int m = e1 - base; if (m > 64) m = 64;
    int j = 0;
    for (; j + 8 <= m; j += 8) {
      float vv[8], ww[8];
#pragma unroll
      for (int q = 0; q < 8; ++q) {
        unsigned rr = (unsigned)__builtin_amdgcn_readlane(mx, j + q);
        vv[q] = u2f(hus[(rr << 6) + lane]);
        ww[q] = __uint_as_float(__builtin_amdgcn_readlane(my, j + q));
      }
#pragma unroll
      for (int q = 0; q < 8; ++q) acc += vv[q] * ww[q];
    }
    for (; j < m; ++j) {
      unsigned rr = (unsigned)__builtin_amdgcn_readlane(mx, j);
      float ww = __uint_as_float(__builtin_amdgcn_readlane(my, j));
      acc += u2f(hus[(rr << 6) + lane]) * ww;
    }
  }
  float mv = mishf(acc + u2f(((const unsigned short*)bias)[lane]));
  uint4 wr = ((const uint4*)Wro)[lane];
  float p0 = mv * lo16(wr.x), p1 = mv * hi16(wr.x);
  float p2 = mv * lo16(wr.y), p3 = mv * hi16(wr.y);
  float p4 = mv * lo16(wr.z), p5 = mv * hi16(wr.z);
  float p6 = mv * lo16(wr.w), p7 = mv * hi16(wr.w);
  bool b0 = lane & 1;
  float q0 = (b0 ? p4 : p0) + __shfl_xor(b0 ? p0 : p4, 1);
  float q1 = (b0 ? p5 : p1) + __shfl_xor(b0 ? p1 : p5, 1);
  float q2 = (b0 ? p6 : p2) + __shfl_xor(b0 ? p2 : p6, 1);
  float q3 = (b0 ? p7 : p3) + __shfl_xor(b0 ? p3 : p7, 1);
  bool b1 = lane & 2;
  float r0 = (b1 ? q2 : q0) + __shfl_xor(b1 ? q0 : q2, 2);
  float r1 = (b1 ? q3 : q1) + __shfl_xor(b1 ? q1 : q3, 2);
  bool b2v = lane & 4;
  float t = (b2v ? r1 : r0) + __shfl_xor(b2v ? r0 : r1, 4);
  t += __shfl_xor(t, 8);
  t += __shfl_xor(t, 16);
  t += __shfl_xor(t, 32);
  if (lane < 8) {
    int oidx = ((lane & 1) << 2) | (lane & 2) | ((lane >> 2) & 1);
    out8[(size_t)n * 8 + oidx] = mishf(t + u2f(((const unsigned short*)bro)[oidx]));
  }
}

// ---------------- dense tail ----------------

__global__ __launch_bounds__(256) void fc1_kernel(const float* __restrict__ feat,
                                                  const bf16* __restrict__ W,
                                                  const bf16* __restrict__ bias,
                                                  float* __restrict__ z) {
  __shared__ float fr[1600];
  int b = blockIdx.x, tid = threadIdx.x;
  for (int i = tid; i < 1600; i += 256) fr[i] = feat[(size_t)b * 1600 + i];
  __syncthreads();
  if (tid < NROI) {
    float acc = b2f(bias[tid]);
#pragma unroll 8
    for (int k = 0; k < 1600; ++k) acc += fr[k] * b2f(W[k * NROI + tid]);
    z[b * NROI + tid] = acc;
  }
}

__global__ __launch_bounds__(256) void bn_stats(const float* __restrict__ z,
                                                float* mu, float* rvar, int B) {
  int j = blockIdx.x;
  int tid = threadIdx.x;
  float v = z[tid * NROI + j];
  float s = v, q = v * v;
  for (int off = 32; off > 0; off >>= 1) {
    s += __shfl_down(s, off);
    q += __shfl_down(q, off);
  }
  __shared__ float ss[4], qq[4];
  int w = tid >> 6, lane = tid & 63;
  if (lane == 0) { ss[w] = s; qq[w] = q; }
  __syncthreads();
  if (tid == 0) {
    float S = ss[0] + ss[1] + ss[2] + ss[3];
    float Q = qq[0] + qq[1] + qq[2] + qq[3];
    float m = S / (float)B;
    float var = Q / (float)B - m * m;
    mu[j] = m;
    rvar[j] = rsqrtf(var + 1e-5f);
  }
}

__global__ __launch_bounds__(256) void head_kernel(const float* __restrict__ z,
                                                   const float* __restrict__ mu,
                                                   const float* __restrict__ rvar,
                                                   const bf16* __restrict__ gamma,
                                                   const bf16* __restrict__ beta,
                                                   const bf16* __restrict__ Wfc2,
                                                   const bf16* __restrict__ bfc2,
                                                   const bf16* __restrict__ Wd1,
                                                   const bf16* __restrict__ bd1,
                                                   const bf16* __restrict__ Wd2,
                                                   const bf16* __restrict__ bd2,
                                                   float* __restrict__ out, int B) {
  __shared__ float mid[NROI];
  __shared__ float t[64];
  int b = blockIdx.x, tid = threadIdx.x;
  if (tid < NROI) {
    float v = (z[b * NROI + tid] - mu[tid]) * rvar[tid] * b2f(gamma[tid]) + b2f(beta[tid]);
    mid[tid] = mishf(v);
  }
  __syncthreads();
  if (tid < 64) {
    float acc = b2f(bd1[tid]);
#pragma unroll 8
    for (int j = 0; j < NROI; ++j) acc += mid[j] * b2f(Wd1[j * 64 + tid]);
    t[tid] = fmaxf(acc, 0.0f);
  }
  if (tid >= 64 && tid < 66) {
    int c = tid - 64;
    float acc = b2f(bfc2[c]);
    for (int j = 0; j < NROI; ++j) acc += mid[j] * b2f(Wfc2[j * 2 + c]);
    out[b * 2 + c] = acc;
  }
  __syncthreads();
  if (tid < 6) {
    float acc = b2f(bd2[tid]);
#pragma unroll 8
    for (int k = 0; k < 64; ++k) acc += t[k] * b2f(Wd2[k * 6 + tid]);
    out[B * 2 + b * 6 + tid] = acc;
  }
}

// ---------------- launch ----------------

extern "C" void kernel_launch(void* const* d_in, const int* in_sizes, int n_in,
                              void* d_out, int out_size, void* d_ws, size_t ws_size,
                              hipStream_t stream) {
  const void* x  = d_in[0];
  const int*  ei = (const int*)d_in[1];
  const void* ea = d_in[2];
  float* out = (float*)d_out;

  int N = in_sizes[0] / NROI;   // 51200
  int E = in_sizes[2];          // 1638400
  int B = N / NROI;             // 256

  int NU = (N + 3) / 4;         // 12800
  int NW = (N + 1) / 2;         // 25600
  int nblk = (E + EPB - 1) / EPB;  // 256
  int bpg = (nblk + 3) / 4;        // 64
  int nsb = (E + SPB - 1) / SPB;   // 256

  char* p = (char*)d_ws;
  auto carve = [&](size_t bytes) -> void* {
    void* r = (void*)p;
    p += (bytes + 255) & ~(size_t)255;
    return r;
  };
  int*   flags = (int*)carve(16);
  bf16*  cw    = (bf16*)carve(400000 * 2);
  float* dis   = (float*)carve((size_t)N * 4);
  unsigned* cnt8g  = (unsigned*)carve((size_t)nblk * NU * 4);
  unsigned* ws16g  = (unsigned*)carve((size_t)nblk * NW * 4);
  unsigned* cntpart = (unsigned*)carve((size_t)4 * NU * 4);
  unsigned* wspart  = (unsigned*)carve((size_t)4 * NU * 16);
  unsigned* gybase  = (unsigned*)carve((size_t)4 * NU * 4);
  unsigned char* rank8 = (unsigned char*)carve((size_t)E);
  int*   cnt   = (int*)carve((size_t)N * 4);
  int*   ptr   = (int*)carve(((size_t)N + 1) * 4);
  int*   bsum  = (int*)carve(1024);
  long long* epair = (long long*)carve((size_t)E * 8);
  unsigned short* h = (unsigned short*)carve((size_t)N * 128 * 2);
  unsigned* g = (unsigned*)carve((size_t)N * 128 * 2);
  unsigned short* w1swz = (unsigned short*)carve(7 * 8 * 512 * 2);
  unsigned short* w2swz = (unsigned short*)carve(4 * 4 * 512 * 2);
  float* out8  = (float*)carve((size_t)N * 8 * 4);
  float* z     = (float*)carve((size_t)B * NROI * 4);
  float* mu    = (float*)carve(NROI * 4);
  float* rv    = (float*)carve(NROI * 4);

  WArgs wa;
  int run = 0;
  int maxn = 0;
  for (int t = 0; t < 16; ++t) {
    wa.src[t] = d_in[3 + t];
    wa.n[t]   = in_sizes[3 + t];
    wa.off[t] = run;
    run += in_sizes[3 + t];
    if (in_sizes[3 + t] > maxn) maxn = in_sizes[3 + t];
  }
  const bf16* W1   = cw + wa.off[0];
  const bf16* b1   = cw + wa.off[1];
  const bf16* W2   = cw + wa.off[2];
  const bf16* b2   = cw + wa.off[3];
  const bf16* Wro  = cw + wa.off[4];
  const bf16* bro  = cw + wa.off[5];
  const bf16* Wfc1 = cw + wa.off[6];
  const bf16* bfc1 = cw + wa.off[7];
  const bf16* gam  = cw + wa.off[8];
  const bf16* bet  = cw + wa.off[9];
  const bf16* Wfc2 = cw + wa.off[10];
  const bf16* bfc2 = cw + wa.off[11];
  const bf16* Wd1  = cw + wa.off[12];
  const bf16* bd1  = cw + wa.off[13];
  const bf16* Wd2  = cw + wa.off[14];
  const bf16* bd2  = cw + wa.off[15];

  detect_kernel<<<1, 256, 0, stream>>>((const unsigned short*)x,
                                       (const unsigned*)ei, flags);
  dim3 wg((maxn + 255) / 256, 18);   // 16 tensors + 2 swizzles
  convert_weights<<<wg, 256, 0, stream>>>(wa, cw, w1swz, w2swz, flags);

  size_t cntLds = (size_t)(NU + NW) * 4;   // 150 KB
  count_lds<<<nblk, 1024, cntLds, stream>>>(ei, ea, flags, cnt8g, ws16g,
                                            rank8, NU, NW, E);
  dim3 rg((NU + 255) / 256, 4);
  reduce_r1<<<rg, 256, 0, stream>>>(cnt8g, ws16g, cntpart, wspart,
                                    NU, NW, nblk, bpg);
  int ncomb = (NU + 255) / 256;            // 50 blocks of 1024 nodes
  combine_k<<<ncomb, 256, 0, stream>>>(cntpart, wspart, gybase, cnt, dis,
                                       bsum, NU, N);
  scan_phase3<<<ncomb, 256, 0, stream>>>(cnt, bsum, ptr, ncomb, N);

  size_t scLds = (size_t)2 * NU * 4;       // 100 KB
  scatter_lds<<<nsb, 1024, scLds, stream>>>(ei, ea, flags, dis, ptr, cnt8g,
                                            gybase, rank8, epair, NU, bpg, E);

  gemm_mfma<7, 8, 1><<<N / 64, 256, 0, stream>>>(x, 200, flags, w1swz, h, N);
  agg_mish128<<<N / 4, 256, 0, stream>>>((const unsigned*)h, dis, ptr, epair,
                                         b1, g, N);
  gemm_mfma<4, 4, 0><<<N / 64, 256, 0, stream>>>(g, 128, flags, w2swz, h, N);
  agg_mish64_ro<<<N / 4, 256, 0, stream>>>(h, dis, ptr, epair, b2, Wro, bro,
                                           out8, N);

  fc1_kernel<<<B, 256, 0, stream>>>(out8, Wfc1, bfc1, z);
  bn_stats<<<NROI, 256, 0, stream>>>(z, mu, rv, B);
  head_kernel<<<B, 256, 0, stream>>>(z, mu, rv, gam, bet, Wfc2, bfc2,
                                     Wd1, bd1, Wd2, bd2, out, B);
}

// Round 14
// 348.542 us; speedup vs baseline: 1.0788x; 1.0788x over previous
//
#include <hip/hip_runtime.h>
#include <hip/hip_bf16.h>

typedef __hip_bfloat16 bf16;
typedef __attribute__((ext_vector_type(8))) short short8;
typedef __attribute__((ext_vector_type(4))) float f32x4;

#define NROI 200
#define EPB 12800   // edges per count block
#define SPB 6400    // edges per scatter block (EPB == 2*SPB)

__device__ __forceinline__ float u2f(unsigned short u) {
  return __uint_as_float(((unsigned)u) << 16);
}
__device__ __forceinline__ float lo16(unsigned u) { return __uint_as_float(u << 16); }
__device__ __forceinline__ float hi16(unsigned u) { return __uint_as_float(u & 0xffff0000u); }
__device__ __forceinline__ float b2f(bf16 v) { return __bfloat162float(v); }
__device__ __forceinline__ unsigned short f2us(float f) {
  union { bf16 b; unsigned short u; } c;
  c.b = __float2bfloat16(f);
  return c.u;
}

__device__ __forceinline__ float mishf(float x) {
  float sp = (x > 20.0f) ? x : log1pf(expf(x));
  return x * tanhf(sp);
}

// ---------------- dtype detection ----------------
__global__ __launch_bounds__(256) void detect_kernel(const unsigned short* xu,
                                                     const unsigned* eiw,
                                                     int* flags) {
  int tid = threadIdx.x;
  int sane = 0, zodd = 0;
  for (int i = tid; i < 4096; i += 256) {
    unsigned short u = xu[2 * i];
    unsigned e = (u >> 7) & 0xFF;
    if (u == 0 || (e >= 100 && e <= 134)) sane++;
  }
  for (int i = tid; i < 4096; i += 256) {
    if (eiw[2 * i + 1] == 0) zodd++;
  }
  __shared__ int s1[256], s2[256];
  s1[tid] = sane; s2[tid] = zodd;
  __syncthreads();
  for (int off = 128; off > 0; off >>= 1) {
    if (tid < off) { s1[tid] += s1[tid + off]; s2[tid] += s2[tid + off]; }
    __syncthreads();
  }
  if (tid == 0) {
    flags[0] = (s1[0] < 2048) ? 1 : 0;
    flags[1] = (s2[0] > 2048) ? 1 : 0;
  }
}

// ---------------- weight canonicalization + swizzles (merged) ----------------
struct WArgs {
  const void* src[16];
  int n[16];
  int off[16];
};

__global__ __launch_bounds__(256) void convert_weights(WArgs a, bf16* base,
                                                       unsigned short* __restrict__ w1swz,
                                                       unsigned short* __restrict__ w2swz,
                                                       const int* flags) {
  int t = blockIdx.y;
  int i = blockIdx.x * 256 + threadIdx.x;
  int isf32 = flags[0];
  if (t < 16) {
    if (i >= a.n[t]) return;
    bf16* dst = base + a.off[t];
    if (isf32) dst[i] = __float2bfloat16(((const float*)a.src[t])[i]);
    else ((unsigned short*)dst)[i] = ((const unsigned short*)a.src[t])[i];
    return;
  }
  int w1 = (t == 16);
  int K  = w1 ? 200 : 128;
  int NT = w1 ? 8 : 4;
  int KC = w1 ? 7 : 4;
  int total = KC * NT * 512;
  if (i >= total) return;
  int e = i & 7;
  int l = (i >> 3) & 63;
  int tt = (i >> 9) % NT;
  int kc = i / (NT * 512);
  int k = kc * 32 + (l >> 4) * 8 + e;
  int c = tt * 16 + (l & 15);
  unsigned short v = 0;
  if (k < K) {
    const void* src = w1 ? a.src[0] : a.src[2];
    if (isf32) v = f2us(((const float*)src)[k * (NT * 16) + c]);
    else v = ((const unsigned short*)src)[k * (NT * 16) + c];
  }
  (w1 ? w1swz : w2swz)[i] = v;
}

// ---------------- LDS-histogram CSR build ----------------

__global__ __launch_bounds__(1024, 1) void count_lds(const int* __restrict__ ei,
                                                     const void* __restrict__ ea,
                                                     const int* __restrict__ flags,
                                                     unsigned* __restrict__ cnt8g,
                                                     unsigned* __restrict__ ws16g,
                                                     unsigned char* __restrict__ rank8,
                                                     int NU, int NW, int E) {
  extern __shared__ unsigned smem[];
  unsigned* s_cnt = smem;        // NU u32
  unsigned* s_ws  = smem + NU;   // NW u32
  int tid = threadIdx.x;
  int blk = blockIdx.x;
  for (int i = tid; i < NU + NW; i += 1024) smem[i] = 0;
  __syncthreads();
  int is64 = flags[1], isf32 = flags[0];
  long long base = (long long)blk * EPB;
  for (int k = 0; k < EPB; k += 1024) {
    int ko = k + tid;
    long long e = base + ko;
    if (ko < EPB && e < E) {
      int c = is64 ? __builtin_nontemporal_load(&ei[2 * ((long long)E + e)])
                   : __builtin_nontemporal_load(&ei[(long long)E + e]);
      float w = isf32 ? __builtin_nontemporal_load(&((const float*)ea)[e])
                      : u2f(__builtin_nontemporal_load(&((const unsigned short*)ea)[e]));
      w = fminf(fmaxf(w, 0.0f), 15.0f);
      unsigned sh = (unsigned)(c & 3) * 8;
      unsigned old = atomicAdd(&s_cnt[c >> 2], 1u << sh);
      rank8[e] = (unsigned char)((old >> sh) & 0xFF);
      unsigned wi = __float2uint_rn(w * 4096.0f);
      atomicAdd(&s_ws[c >> 1], (c & 1) ? (wi << 16) : wi);
    }
  }
  __syncthreads();
  for (int i = tid; i < NU; i += 1024)
    __builtin_nontemporal_store(s_cnt[i], &cnt8g[(size_t)blk * NU + i]);
  for (int i = tid; i < NW; i += 1024)
    __builtin_nontemporal_store(s_ws[i], &ws16g[(size_t)blk * NW + i]);
}

__global__ __launch_bounds__(256) void reduce_r1(unsigned* __restrict__ cnt8g,
                                                 const unsigned* __restrict__ ws16g,
                                                 unsigned* __restrict__ cntpart,
                                                 unsigned* __restrict__ wspart,
                                                 int NU, int NW, int nblk, int bpg) {
  int col = blockIdx.x * 256 + threadIdx.x;
  int gy = blockIdx.y;
  if (col >= NU) return;
  unsigned run = 0;
  unsigned r0 = 0, r1 = 0, r2 = 0, r3 = 0;
  int b0 = gy * bpg;
  int be = b0 + bpg; if (be > nblk) be = nblk;
  for (int b = b0; b < be; ++b) {
    unsigned v = cnt8g[(size_t)b * NU + col];
    cnt8g[(size_t)b * NU + col] = run;
    run += v;                       // SWAR-safe: per-node totals < 256
    unsigned wA = ws16g[(size_t)b * NW + 2 * col];
    unsigned wB = ws16g[(size_t)b * NW + 2 * col + 1];
    r0 += wA & 0xFFFF; r1 += wA >> 16;
    r2 += wB & 0xFFFF; r3 += wB >> 16;
  }
  cntpart[(size_t)gy * NU + col] = run;
  unsigned* wp = &wspart[((size_t)gy * NU + col) * 4];
  wp[0] = r0; wp[1] = r1; wp[2] = r2; wp[3] = r3;
}

// 4-group prefix -> gybase; totals -> cnt[n]; dis; + per-1024-node block sums
__global__ __launch_bounds__(256) void combine_k(const unsigned* __restrict__ cntpart,
                                                 const unsigned* __restrict__ wspart,
                                                 unsigned* __restrict__ gybase,
                                                 int* __restrict__ cnt,
                                                 float* __restrict__ dis,
                                                 int* __restrict__ bsum,
                                                 int NU, int N) {
  __shared__ int ts[256];
  int col = blockIdx.x * 256 + threadIdx.x;
  int mysum = 0;
  if (col < NU) {
    unsigned g = 0;
#pragma unroll
    for (int gy = 0; gy < 4; ++gy) {
      unsigned t = cntpart[(size_t)gy * NU + col];
      gybase[(size_t)gy * NU + col] = g;
      g += t;
    }
    unsigned ws[4] = {0, 0, 0, 0};
#pragma unroll
    for (int gy = 0; gy < 4; ++gy) {
      const unsigned* wp = &wspart[((size_t)gy * NU + col) * 4];
#pragma unroll
      for (int j = 0; j < 4; ++j) ws[j] += wp[j];
    }
#pragma unroll
    for (int j = 0; j < 4; ++j) {
      int n = 4 * col + j;
      if (n < N) {
        int cj = (int)((g >> (8 * j)) & 0xFF);
        cnt[n] = cj;
        mysum += cj;
        dis[n] = rsqrtf(1.0f + (float)ws[j] * 0.000244140625f);
      }
    }
  }
  int tid = threadIdx.x;
  ts[tid] = mysum;
  __syncthreads();
  for (int off = 128; off > 0; off >>= 1) {
    if (tid < off) ts[tid] += ts[tid + off];
    __syncthreads();
  }
  if (tid == 0) bsum[blockIdx.x] = ts[0];
}

// scan over cnt -> ptr; per-block base computed inline from bsum (phase2 folded)
__global__ __launch_bounds__(256) void scan_phase3(const int* __restrict__ cnt,
                                                   const int* __restrict__ bsum,
                                                   int* __restrict__ ptr,
                                                   int nb, int N) {
  __shared__ int ts[256];
  int blk = blockIdx.x;
  int tid = threadIdx.x;
  int bpre = 0;
  for (int i = 0; i < blk; ++i) bpre += bsum[i];
  int base = blk * 1024 + tid * 4;
  int c0 = 0, c1 = 0, c2 = 0, c3 = 0;
  if (base + 0 < N) c0 = cnt[base + 0];
  if (base + 1 < N) c1 = cnt[base + 1];
  if (base + 2 < N) c2 = cnt[base + 2];
  if (base + 3 < N) c3 = cnt[base + 3];
  ts[tid] = c0 + c1 + c2 + c3;
  __syncthreads();
  for (int off = 1; off < 256; off <<= 1) {
    int v = ts[tid];
    if (tid >= off) v += ts[tid - off];
    __syncthreads();
    ts[tid] = v;
    __syncthreads();
  }
  int run = bpre + (tid ? ts[tid - 1] : 0);
  if (base + 0 < N) { ptr[base + 0] = run; run += c0; }
  if (base + 1 < N) { ptr[base + 1] = run; run += c1; }
  if (base + 2 < N) { ptr[base + 2] = run; run += c2; }
  if (base + 3 < N) { ptr[base + 3] = run; run += c3; }
  if (blk == nb - 1 && tid == 255) ptr[N] = bpre + ts[255];
}

// atomic-free scatter: 4B packed (r:16 | bf16(dis[r]*w):16)
__global__ __launch_bounds__(1024, 1) void scatter_lds(const int* __restrict__ ei,
                                                       const void* __restrict__ ea,
                                                       const int* __restrict__ flags,
                                                       const float* __restrict__ dis,
                                                       const int* __restrict__ ptr,
                                                       const unsigned* __restrict__ cnt8g,
                                                       const unsigned* __restrict__ gybase,
                                                       const unsigned char* __restrict__ rank8,
                                                       unsigned* __restrict__ epair,
                                                       int NU, int bpg, int E) {
  extern __shared__ unsigned smem[];
  unsigned* s_pb = smem;        // per-count-block bases
  unsigned* s_gb = smem + NU;   // group bases
  int tid = threadIdx.x;
  int blk = blockIdx.x;
  int cblk = blk >> 1;          // count block (EPB == 2*SPB)
  int gy = cblk / bpg;
  for (int i = tid; i < NU; i += 1024) s_pb[i] = cnt8g[(size_t)cblk * NU + i];
  for (int i = tid; i < NU; i += 1024) s_gb[i] = gybase[(size_t)gy * NU + i];
  __syncthreads();
  int is64 = flags[1], isf32 = flags[0];
  long long base = (long long)blk * SPB;
  for (int k = 0; k < SPB; k += 1024) {
    int ko = k + tid;
    long long e = base + ko;
    if (ko < SPB && e < E) {
      int r = is64 ? __builtin_nontemporal_load(&ei[2 * e])
                   : __builtin_nontemporal_load(&ei[e]);
      int c = is64 ? __builtin_nontemporal_load(&ei[2 * ((long long)E + e)])
                   : __builtin_nontemporal_load(&ei[(long long)E + e]);
      float w = isf32 ? __builtin_nontemporal_load(&((const float*)ea)[e])
                      : u2f(__builtin_nontemporal_load(&((const unsigned short*)ea)[e]));
      float disw = dis[r] * w;
      unsigned sh = (unsigned)(c & 3) * 8;
      unsigned p1 = (s_pb[c >> 2] >> sh) & 0xFF;
      unsigned p2 = (s_gb[c >> 2] >> sh) & 0xFF;
      int idx = ptr[c] + (int)p1 + (int)p2 + (int)rank8[e];
      unsigned pr = ((unsigned)r << 16) | f2us(disw);
      __builtin_nontemporal_store(pr, &epair[idx]);
    }
  }
}

// ---------------- MFMA GEMM ----------------
template<int KC, int NT, int DYN>
__global__ __launch_bounds__(256) void gemm_mfma(const void* __restrict__ A,
                                                 int Ktrue,
                                                 const int* __restrict__ flags,
                                                 const unsigned short* __restrict__ Wswz,
                                                 unsigned short* __restrict__ H,
                                                 int M) {
  int wid = threadIdx.x >> 6, lane = threadIdx.x & 63;
  int row0 = (blockIdx.x * 4 + wid) * 16;
  if (row0 >= M) return;
  constexpr int NC = NT * 16;
  int isf32 = DYN ? flags[0] : 0;
  f32x4 acc[NT];
#pragma unroll
  for (int t = 0; t < NT; ++t) acc[t] = {0.f, 0.f, 0.f, 0.f};
  int arow = row0 + (lane & 15);
  int kbase = (lane >> 4) * 8;
  const float* Af = (const float*)A;
  const unsigned short* Au = (const unsigned short*)A;
#pragma unroll
  for (int kc = 0; kc < KC; ++kc) {
    int k0 = kbase + kc * 32;
    short8 a = {0, 0, 0, 0, 0, 0, 0, 0};
    if (k0 + 8 <= Ktrue) {
      size_t off = (size_t)arow * Ktrue + k0;
      if (DYN && isf32) {
        f32x4 f0 = __builtin_nontemporal_load((const f32x4*)&Af[off]);
        f32x4 f1 = __builtin_nontemporal_load((const f32x4*)&Af[off + 4]);
        a[0] = (short)f2us(f0[0]); a[1] = (short)f2us(f0[1]);
        a[2] = (short)f2us(f0[2]); a[3] = (short)f2us(f0[3]);
        a[4] = (short)f2us(f1[0]); a[5] = (short)f2us(f1[1]);
        a[6] = (short)f2us(f1[2]); a[7] = (short)f2us(f1[3]);
      } else {
        a = *(const short8*)&Au[off];
      }
    }
#pragma unroll
    for (int t = 0; t < NT; ++t) {
      short8 b = *(const short8*)&Wswz[((kc * NT + t) * 64 + lane) * 8];
      acc[t] = __builtin_amdgcn_mfma_f32_16x16x32_bf16(a, b, acc[t], 0, 0, 0);
    }
  }
  int orow = row0 + (lane >> 4) * 4;
  int ocol = lane & 15;
#pragma unroll
  for (int t = 0; t < NT; ++t)
#pragma unroll
    for (int r = 0; r < 4; ++r)
      H[(size_t)(orow + r) * NC + t * 16 + ocol] = f2us(acc[t][r]);
}

// ---------------- aggregations ----------------
// out = mish(dis[n]*(h[n]*dis[n] + sum h[r]*disw_e) + bias)
// conv1: full wave per node; lane owns uint 'lane' (2 of 128 feats).
__global__ __launch_bounds__(256) void agg_mish128(const unsigned* __restrict__ hu,
                                                   const float* __restrict__ dis,
                                                   const int* __restrict__ ptr,
                                                   const unsigned* __restrict__ ep,
                                                   const bf16* __restrict__ bias,
                                                   unsigned* __restrict__ g, int N) {
  int w = threadIdx.x >> 6, lane = threadIdx.x & 63;
  int n = blockIdx.x * 4 + w;
  float dn = dis[n];
  unsigned u = hu[((unsigned)n << 6) + lane];
  float acc0 = lo16(u) * dn;
  float acc1 = hi16(u) * dn;
  int e0 = ptr[n], e1 = ptr[n + 1];
  for (int base = e0; base < e1; base += 64) {
    unsigned myp = 0;
    if (base + lane < e1) myp = __builtin_nontemporal_load(&ep[base + lane]);
    int m = e1 - base; if (m > 64) m = 64;
    int j = 0;
    for (; j + 8 <= m; j += 8) {
      unsigned uu[8]; float ww[8];
#pragma unroll
      for (int q = 0; q < 8; ++q) {
        unsigned pk = (unsigned)__builtin_amdgcn_readlane((int)myp, j + q);
        uu[q] = hu[((pk >> 16) << 6) + lane];
        ww[q] = u2f((unsigned short)pk);
      }
#pragma unroll
      for (int q = 0; q < 8; ++q) {
        acc0 += lo16(uu[q]) * ww[q];
        acc1 += hi16(uu[q]) * ww[q];
      }
    }
    for (; j < m; ++j) {
      unsigned pk = (unsigned)__builtin_amdgcn_readlane((int)myp, j);
      unsigned uu = hu[((pk >> 16) << 6) + lane];
      float ww = u2f((unsigned short)pk);
      acc0 += lo16(uu) * ww;
      acc1 += hi16(uu) * ww;
    }
  }
  unsigned bb = ((const unsigned*)bias)[lane];
  float m0 = mishf(acc0 * dn + lo16(bb));
  float m1 = mishf(acc1 * dn + hi16(bb));
  __builtin_nontemporal_store(((unsigned)f2us(m1) << 16) | f2us(m0),
                              &g[((unsigned)n << 6) + lane]);
}

// conv2 + readout: full wave per node; lane owns ONE of 64 feats.
__global__ __launch_bounds__(256) void agg_mish64_ro(const unsigned short* __restrict__ hus,
                                                     const float* __restrict__ dis,
                                                     const int* __restrict__ ptr,
                                                     const unsigned* __restrict__ ep,
                                                     const bf16* __restrict__ bias,
                                                     const bf16* __restrict__ Wro,
                                                     const bf16* __restrict__ bro,
                                                     float* __restrict__ out8, int N) {
  int w = threadIdx.x >> 6, lane = threadIdx.x & 63;
  int n = blockIdx.x * 4 + w;
  float dn = dis[n];
  float acc = u2f(hus[((unsigned)n << 6) + lane]) * dn;
  int e0 = ptr[n], e1 = ptr[n + 1];
  for (int base = e0; base < e1; base += 64) {
    unsigned myp = 0;
    if (base + lane < e1) myp = __builtin_nontemporal_load(&ep[base + lane]);
    int m = e1 - base; if (m > 64) m = 64;
    int j = 0;
    for (; j + 8 <= m; j += 8) {
      float vv[8], ww[8];
#pragma unroll
      for (int q = 0; q < 8; ++q) {
        unsigned pk = (unsigned)__builtin_amdgcn_readlane((int)myp, j + q);
        vv[q] = u2f(hus[((pk >> 16) << 6) + lane]);
        ww[q] = u2f((unsigned short)pk);
      }
#pragma unroll
      for (int q = 0; q < 8; ++q) acc += vv[q] * ww[q];
    }
    for (; j < m; ++j) {
      unsigned pk = (unsigned)__builtin_amdgcn_readlane((int)myp, j);
      acc += u2f(hus[((pk >> 16) << 6) + lane]) * u2f((unsigned short)pk);
    }
  }
  float mv = mishf(acc * dn + u2f(((const unsigned short*)bias)[lane]));
  uint4 wr = ((const uint4*)Wro)[lane];
  float p0 = mv * lo16(wr.x), p1 = mv * hi16(wr.x);
  float p2 = mv * lo16(wr.y), p3 = mv * hi16(wr.y);
  float p4 = mv * lo16(wr.z), p5 = mv * hi16(wr.z);
  float p6 = mv * lo16(wr.w), p7 = mv * hi16(wr.w);
  bool b0 = lane & 1;
  float q0 = (b0 ? p4 : p0) + __shfl_xor(b0 ? p0 : p4, 1);
  float q1 = (b0 ? p5 : p1) + __shfl_xor(b0 ? p1 : p5, 1);
  float q2 = (b0 ? p6 : p2) + __shfl_xor(b0 ? p2 : p6, 1);
  float q3 = (b0 ? p7 : p3) + __shfl_xor(b0 ? p3 : p7, 1);
  bool b1 = lane & 2;
  float r0 = (b1 ? q2 : q0) + __shfl_xor(b1 ? q0 : q2, 2);
  float r1 = (b1 ? q3 : q1) + __shfl_xor(b1 ? q1 : q3, 2);
  bool b2v = lane & 4;
  float t = (b2v ? r1 : r0) + __shfl_xor(b2v ? r0 : r1, 4);
  t += __shfl_xor(t, 8);
  t += __shfl_xor(t, 16);
  t += __shfl_xor(t, 32);
  if (lane < 8) {
    int oidx = ((lane & 1) << 2) | (lane & 2) | ((lane >> 2) & 1);
    out8[(size_t)n * 8 + oidx] = mishf(t + u2f(((const unsigned short*)bro)[oidx]));
  }
}

// ---------------- dense tail ----------------

__global__ __launch_bounds__(256) void fc1_kernel(const float* __restrict__ feat,
                                                  const bf16* __restrict__ W,
                                                  const bf16* __restrict__ bias,
                                                  float* __restrict__ z) {
  __shared__ float fr[1600];
  int b = blockIdx.x, tid = threadIdx.x;
  for (int i = tid; i < 1600; i += 256) fr[i] = feat[(size_t)b * 1600 + i];
  __syncthreads();
  if (tid < NROI) {
    float acc = b2f(bias[tid]);
#pragma unroll 8
    for (int k = 0; k < 1600; ++k) acc += fr[k] * b2f(W[k * NROI + tid]);
    z[b * NROI + tid] = acc;
  }
}

__global__ __launch_bounds__(256) void bn_stats(const float* __restrict__ z,
                                                float* mu, float* rvar, int B) {
  int j = blockIdx.x;
  int tid = threadIdx.x;
  float v = z[tid * NROI + j];
  float s = v, q = v * v;
  for (int off = 32; off > 0; off >>= 1) {
    s += __shfl_down(s, off);
    q += __shfl_down(q, off);
  }
  __shared__ float ss[4], qq[4];
  int w = tid >> 6, lane = tid & 63;
  if (lane == 0) { ss[w] = s; qq[w] = q; }
  __syncthreads();
  if (tid == 0) {
    float S = ss[0] + ss[1] + ss[2] + ss[3];
    float Q = qq[0] + qq[1] + qq[2] + qq[3];
    float m = S / (float)B;
    float var = Q / (float)B - m * m;
    mu[j] = m;
    rvar[j] = rsqrtf(var + 1e-5f);
  }
}

__global__ __launch_bounds__(256) void head_kernel(const float* __restrict__ z,
                                                   const float* __restrict__ mu,
                                                   const float* __restrict__ rvar,
                                                   const bf16* __restrict__ gamma,
                                                   const bf16* __restrict__ beta,
                                                   const bf16* __restrict__ Wfc2,
                                                   const bf16* __restrict__ bfc2,
                                                   const bf16* __restrict__ Wd1,
                                                   const bf16* __restrict__ bd1,
                                                   const bf16* __restrict__ Wd2,
                                                   const bf16* __restrict__ bd2,
                                                   float* __restrict__ out, int B) {
  __shared__ float mid[NROI];
  __shared__ float t[64];
  int b = blockIdx.x, tid = threadIdx.x;
  if (tid < NROI) {
    float v = (z[b * NROI + tid] - mu[tid]) * rvar[tid] * b2f(gamma[tid]) + b2f(beta[tid]);
    mid[tid] = mishf(v);
  }
  __syncthreads();
  if (tid < 64) {
    float acc = b2f(bd1[tid]);
#pragma unroll 8
    for (int j = 0; j < NROI; ++j) acc += mid[j] * b2f(Wd1[j * 64 + tid]);
    t[tid] = fmaxf(acc, 0.0f);
  }
  if (tid >= 64 && tid < 66) {
    int c = tid - 64;
    float acc = b2f(bfc2[c]);
    for (int j = 0; j < NROI; ++j) acc += mid[j] * b2f(Wfc2[j * 2 + c]);
    out[b * 2 + c] = acc;
  }
  __syncthreads();
  if (tid < 6) {
    float acc = b2f(bd2[tid]);
#pragma unroll 8
    for (int k = 0; k < 64; ++k) acc += t[k] * b2f(Wd2[k * 6 + tid]);
    out[B * 2 + b * 6 + tid] = acc;
  }
}

// ---------------- launch ----------------

extern "C" void kernel_launch(void* const* d_in, const int* in_sizes, int n_in,
                              void* d_out, int out_size, void* d_ws, size_t ws_size,
                              hipStream_t stream) {
  const void* x  = d_in[0];
  const int*  ei = (const int*)d_in[1];
  const void* ea = d_in[2];
  float* out = (float*)d_out;

  int N = in_sizes[0] / NROI;   // 51200
  int E = in_sizes[2];          // 1638400
  int B = N / NROI;             // 256

  int NU = (N + 3) / 4;         // 12800
  int NW = (N + 1) / 2;         // 25600
  int nblk = (E + EPB - 1) / EPB;  // 128
  int bpg = (nblk + 3) / 4;        // 32
  int nsb = (E + SPB - 1) / SPB;   // 256

  char* p = (char*)d_ws;
  auto carve = [&](size_t bytes) -> void* {
    void* r = (void*)p;
    p += (bytes + 255) & ~(size_t)255;
    return r;
  };
  int*   flags = (int*)carve(16);
  bf16*  cw    = (bf16*)carve(400000 * 2);
  float* dis   = (float*)carve((size_t)N * 4);
  unsigned* cnt8g  = (unsigned*)carve((size_t)nblk * NU * 4);
  unsigned* ws16g  = (unsigned*)carve((size_t)nblk * NW * 4);
  unsigned* cntpart = (unsigned*)carve((size_t)4 * NU * 4);
  unsigned* wspart  = (unsigned*)carve((size_t)4 * NU * 16);
  unsigned* gybase  = (unsigned*)carve((size_t)4 * NU * 4);
  unsigned char* rank8 = (unsigned char*)carve((size_t)E);
  int*   cnt   = (int*)carve((size_t)N * 4);
  int*   ptr   = (int*)carve(((size_t)N + 1) * 4);
  int*   bsum  = (int*)carve(1024);
  unsigned* epair = (unsigned*)carve((size_t)E * 4);
  unsigned short* h = (unsigned short*)carve((size_t)N * 128 * 2);
  unsigned* g = (unsigned*)carve((size_t)N * 128 * 2);
  unsigned short* w1swz = (unsigned short*)carve(7 * 8 * 512 * 2);
  unsigned short* w2swz = (unsigned short*)carve(4 * 4 * 512 * 2);
  float* out8  = (float*)carve((size_t)N * 8 * 4);
  float* z     = (float*)carve((size_t)B * NROI * 4);
  float* mu    = (float*)carve(NROI * 4);
  float* rv    = (float*)carve(NROI * 4);

  WArgs wa;
  int run = 0;
  int maxn = 0;
  for (int t = 0; t < 16; ++t) {
    wa.src[t] = d_in[3 + t];
    wa.n[t]   = in_sizes[3 + t];
    wa.off[t] = run;
    run += in_sizes[3 + t];
    if (in_sizes[3 + t] > maxn) maxn = in_sizes[3 + t];
  }
  const bf16* W1   = cw + wa.off[0];
  const bf16* b1   = cw + wa.off[1];
  const bf16* W2   = cw + wa.off[2];
  const bf16* b2   = cw + wa.off[3];
  const bf16* Wro  = cw + wa.off[4];
  const bf16* bro  = cw + wa.off[5];
  const bf16* Wfc1 = cw + wa.off[6];
  const bf16* bfc1 = cw + wa.off[7];
  const bf16* gam  = cw + wa.off[8];
  const bf16* bet  = cw + wa.off[9];
  const bf16* Wfc2 = cw + wa.off[10];
  const bf16* bfc2 = cw + wa.off[11];
  const bf16* Wd1  = cw + wa.off[12];
  const bf16* bd1  = cw + wa.off[13];
  const bf16* Wd2  = cw + wa.off[14];
  const bf16* bd2  = cw + wa.off[15];

  detect_kernel<<<1, 256, 0, stream>>>((const unsigned short*)x,
                                       (const unsigned*)ei, flags);
  dim3 wg((maxn + 255) / 256, 18);   // 16 tensors + 2 swizzles
  convert_weights<<<wg, 256, 0, stream>>>(wa, cw, w1swz, w2swz, flags);

  size_t cntLds = (size_t)(NU + NW) * 4;   // 150 KB
  count_lds<<<nblk, 1024, cntLds, stream>>>(ei, ea, flags, cnt8g, ws16g,
                                            rank8, NU, NW, E);
  dim3 rg((NU + 255) / 256, 4);
  reduce_r1<<<rg, 256, 0, stream>>>(cnt8g, ws16g, cntpart, wspart,
                                    NU, NW, nblk, bpg);
  int ncomb = (NU + 255) / 256;            // 50 blocks of 1024 nodes
  combine_k<<<ncomb, 256, 0, stream>>>(cntpart, wspart, gybase, cnt, dis,
                                       bsum, NU, N);
  scan_phase3<<<ncomb, 256, 0, stream>>>(cnt, bsum, ptr, ncomb, N);

  size_t scLds = (size_t)2 * NU * 4;       // 100 KB
  scatter_lds<<<nsb, 1024, scLds, stream>>>(ei, ea, flags, dis, ptr, cnt8g,
                                            gybase, rank8, epair, NU, bpg, E);

  gemm_mfma<7, 8, 1><<<N / 64, 256, 0, stream>>>(x, 200, flags, w1swz, h, N);
  agg_mish128<<<N / 4, 256, 0, stream>>>((const unsigned*)h, dis, ptr, epair,
                                         b1, g, N);
  gemm_mfma<4, 4, 0><<<N / 64, 256, 0, stream>>>(g, 128, flags, w2swz, h, N);
  agg_mish64_ro<<<N / 4, 256, 0, stream>>>(h, dis, ptr, epair, b2, Wro, bro,
                                           out8, N);

  fc1_kernel<<<B, 256, 0, stream>>>(out8, Wfc1, bfc1, z);
  bn_stats<<<NROI, 256, 0, stream>>>(z, mu, rv, B);
  head_kernel<<<B, 256, 0, stream>>>(z, mu, rv, gam, bet, Wfc2, bfc2,
                                     Wd1, bd1, Wd2, bd2, out, B);
}